// Round 2
// baseline (195.097 us; speedup 1.0000x reference)
//
#include <hip/hip_runtime.h>
#include <math.h>

// ConvBertLightConv: dynamic depthwise conv with softmax-normalized per-(pos,head) kernels.
// B=8, S=4096, D=768 (12 heads x 64), K=9, 'same' zero padding along S.
// out[b,s,h,d] = sum_k softmax(filters[b,s,h,:])[k] * x[b, s+k-4, h*64+d]
//
// R4: memory-level-parallelism attack. R3 was latency-bound (VALUBusy 6.8%,
// BW 34% of peak): the sliding-window loop kept only ~1 x-load in flight per
// wave (VGPR_Count=32 shows no load pipeline). Now ALL 24 tile rows (16 + 8
// halo) are loaded into registers upfront as independent float4 loads, issued
// AFTER the filter loads (so the filter vmcnt wait leaves x in flight) and
// BEFORE the LDS staging + softmax phases (whose latency they hide under).
// 24 in-flight loads/wave x ~15 waves/CU ~= the ~320-loads/CU Little's-law
// target for 6.3 TB/s streaming.

#define KS 9
#define HD 64
#define NH 12
#define DMODEL 768             // NH*HD
#define SEQ 4096
#define BATCH 8
#define TTILE 16               // s-positions per block
#define NROWS (TTILE + KS - 1) // 24 x-rows per tile (incl. halo)
#define CHUNKS (SEQ / TTILE)   // 256
#define FSTRIDE (NH * KS)      // 108 filter floats per position
#define NTHREADS 192

__global__ __launch_bounds__(NTHREADS, 4) void lightconv_kernel(
    const float* __restrict__ x,      // [B, S, 768]
    const float* __restrict__ filt,   // [B, S, 108]
    float* __restrict__ out)          // [B, S, 768]
{
    __shared__ float wlds[TTILE * FSTRIDE];   // 16*108*4B = 6912 B

    const int blk   = blockIdx.x;             // b * CHUNKS + chunk
    const int chunk = blk & (CHUNKS - 1);
    const int b     = blk >> 8;               // CHUNKS = 256
    const int s0    = chunk * TTILE;
    const int t     = threadIdx.x;            // 0..191
    const int head  = t >> 4;                 // 0..11
    const int d4    = (t & 15) << 2;          // 0,4,...,60

    const float4 zero = make_float4(0.f, 0.f, 0.f, 0.f);

    // ---- 1. filter loads -> registers (coalesced, issued FIRST so the
    //         wait for them leaves the x loads below still outstanding) ----
    const float* fbase = filt + ((size_t)b * SEQ + s0) * FSTRIDE;
    float freg[KS];                           // 16*108/192 = 9 per thread
#pragma unroll
    for (int i = 0; i < KS; ++i) freg[i] = fbase[t + i * NTHREADS];

    // ---- 2. x rows -> registers: 24 INDEPENDENT float4 loads ----
    const float* xc = x + (size_t)b * SEQ * DMODEL + head * HD + d4;
    float4 rows[NROWS];
#pragma unroll
    for (int r = 0; r < NROWS; ++r) {
        const int ss = s0 + r - (KS / 2);
        rows[r] = (ss >= 0 && ss < SEQ)
                    ? *reinterpret_cast<const float4*>(xc + (size_t)ss * DMODEL)
                    : zero;
    }

    // ---- 3. stage filters to LDS (waits only on filter loads) ----
#pragma unroll
    for (int i = 0; i < KS; ++i) wlds[t + i * NTHREADS] = freg[i];
    __syncthreads();

    // ---- 4. one softmax per (s_local, head); 192 pairs == 192 threads.
    //         x loads still in flight underneath. ----
    {
        const int sl = t & 15;                // s_local 0..15
        const int hh = t >> 4;                // head    0..11
        float* wp = &wlds[sl * FSTRIDE + hh * KS];
        float w[KS];
        float m = -1e30f;
#pragma unroll
        for (int k = 0; k < KS; ++k) { w[k] = wp[k]; m = fmaxf(m, w[k]); }
        float sum = 0.f;
#pragma unroll
        for (int k = 0; k < KS; ++k) { w[k] = __expf(w[k] - m); sum += w[k]; }
        const float inv = 1.0f / sum;
#pragma unroll
        for (int k = 0; k < KS; ++k) wp[k] = w[k] * inv;
    }
    __syncthreads();

    // ---- 5. conv: pure register + LDS-broadcast work, progressive vmcnt
    //         drain over the preloaded rows ----
    float* oc = out + (size_t)b * SEQ * DMODEL + head * HD + d4;
#pragma unroll
    for (int i = 0; i < TTILE; ++i) {
        const float* wp = &wlds[i * FSTRIDE + head * KS];  // broadcast to 16 lanes
        float4 acc = zero;
#pragma unroll
        for (int k = 0; k < KS; ++k) {
            const float wk = wp[k];
            acc.x += wk * rows[i + k].x;
            acc.y += wk * rows[i + k].y;
            acc.z += wk * rows[i + k].z;
            acc.w += wk * rows[i + k].w;
        }
        *reinterpret_cast<float4*>(oc + (size_t)(s0 + i) * DMODEL) = acc;
    }
}

extern "C" void kernel_launch(void* const* d_in, const int* in_sizes, int n_in,
                              void* d_out, int out_size, void* d_ws, size_t ws_size,
                              hipStream_t stream) {
    const float* x    = (const float*)d_in[0];   // [8,4096,768] fp32
    const float* filt = (const float*)d_in[1];   // [8,4096,108] fp32
    float* out        = (float*)d_out;           // [8,4096,12,64] fp32

    const int grid = BATCH * CHUNKS;             // 8 * 256 = 2048 blocks
    lightconv_kernel<<<grid, NTHREADS, 0, stream>>>(x, filt, out);
}

// Round 3
// 187.282 us; speedup vs baseline: 1.0417x; 1.0417x over previous
//
#include <hip/hip_runtime.h>
#include <math.h>

// ConvBertLightConv: dynamic depthwise conv with softmax-normalized per-(pos,head) kernels.
// B=8, S=4096, D=768 (12 heads x 64), K=9, 'same' zero padding along S.
// out[b,s,h,d] = sum_k softmax(filters[b,s,h,:])[k] * x[b, s+k-4, h*64+d]
//
// R5: async global_load_lds staging. R4 post-mortem: compiler refused a
// 24-deep VGPR load pipeline (VGPR stayed 64, BW stuck at 2.85 TB/s, 35% of
// peak, VALUBusy 6.8% -> pure exposed latency). global_load_lds is counted
// only by vmcnt and uses no VGPRs, so MLP depth is architectural, not a
// regalloc decision:
//   - block = 32 s x 4 heads; x-tile 40 rows x 1024 B staged by 40 async
//     gll ops (each = one wave-wide 1024 B row, linear LDS dest).
//     ~45 KB in flight per block >> ~5 KB/CU Little's-law need for 6.3 TB/s.
//   - 3 blocks/CU (LDS 45.5 KB) stagger stage/compute phases to cover each
//     other's single vmcnt(0) barrier drain.
//   - filters: one thread owns one (s,head) softmax; its 9 scalar loads are
//     issued BEFORE the gll batch (auto-waitcnt = vmcnt(10), x stays in
//     flight), softmax runs in regs under the gll shadow, result ds_written.
//     sched_barrier(0) pins stop the compiler from reordering issue order.
//   - conv: contiguous wave-wide ds_read_b128 (conflict-free), weight
//     broadcast reads hit banks {0,9,18,27} (conflict-free), coalesced
//     1024 B/wave stores.

#define KS 9
#define HD 64
#define NH 12
#define DMODEL 768             // NH*HD
#define SEQ 4096
#define BATCH 8
#define TTILE 32               // s-positions per block
#define NROWS (TTILE + KS - 1) // 40 x-rows incl. halo
#define HG 4                   // heads per block
#define NHG (NH / HG)          // 3 head-groups
#define DBLK (HG * HD)         // 256 floats per row-slice
#define CHUNKS (SEQ / TTILE)   // 128
#define FSTRIDE (NH * KS)      // 108 filter floats per position
#define FW (HG * KS)           // 36 filter floats per (s, head-group)
#define NTHREADS 256           // 4 waves
#define ROWS_PER_WAVE (NROWS / 4)  // 10

__global__ __launch_bounds__(NTHREADS, 3) void lightconv_kernel(
    const float* __restrict__ x,      // [B, S, 768]
    const float* __restrict__ filt,   // [B, S, 108]
    float* __restrict__ out)          // [B, S, 768]
{
    __shared__ float xs[NROWS * DBLK];   // 40*256*4 = 40960 B
    __shared__ float fwl[TTILE * FW];    // 32*36*4  =  4608 B

    const int blk   = blockIdx.x;             // ((b*NHG + hg) << 7) | chunk
    const int chunk = blk & (CHUNKS - 1);
    const int rest  = blk >> 7;
    const int hg    = rest % NHG;
    const int b     = rest / NHG;
    const int s0    = chunk * TTILE;
    const int t     = threadIdx.x;            // 0..255
    const int wave  = t >> 6;                 // 0..3
    const int lane  = t & 63;

    // ---- 1. filter loads -> registers, issued FIRST so the softmax wait
    //         below is vmcnt(10), leaving the x gll batch in flight ----
    float w[KS];
    if (t < TTILE * HG) {                     // 128 (s,head) pairs
        const int sl = t >> 2;                // s_local 0..31
        const int h  = t & 3;                 // head-in-group 0..3
        const float* fp = filt + ((size_t)b * SEQ + s0 + sl) * FSTRIDE
                               + hg * FW + h * KS;
#pragma unroll
        for (int k = 0; k < KS; ++k) w[k] = fp[k];
    }
    __builtin_amdgcn_sched_barrier(0);

    // ---- 2. async x staging: 10 wave-wide 1024 B rows per wave ----
    //         lane i's 16 B lands at xs[r*256 + i*4] (uniform base + lane*16).
    const float* xrow = x + (size_t)b * SEQ * DMODEL + hg * DBLK + lane * 4;
#pragma unroll
    for (int j = 0; j < ROWS_PER_WAVE; ++j) {
        const int r  = wave * ROWS_PER_WAVE + j;
        const int ss = s0 + r - (KS / 2);
        if (ss >= 0 && ss < SEQ) {            // wave-uniform branch
            __builtin_amdgcn_global_load_lds(
                (const __attribute__((address_space(1))) void*)(xrow + (size_t)ss * DMODEL),
                (__attribute__((address_space(3))) void*)&xs[r * DBLK],
                16, 0, 0);
        } else {
            *reinterpret_cast<float4*>(&xs[r * DBLK + lane * 4]) =
                make_float4(0.f, 0.f, 0.f, 0.f);
        }
    }
    __builtin_amdgcn_sched_barrier(0);

    // ---- 3. softmax in registers (gll still in flight), write to LDS ----
    if (t < TTILE * HG) {
        const int sl = t >> 2;
        const int h  = t & 3;
        float m = -1e30f;
#pragma unroll
        for (int k = 0; k < KS; ++k) m = fmaxf(m, w[k]);
        float sum = 0.f;
#pragma unroll
        for (int k = 0; k < KS; ++k) { w[k] = __expf(w[k] - m); sum += w[k]; }
        const float inv = 1.0f / sum;
        float* wp = &fwl[sl * FW + h * KS];
#pragma unroll
        for (int k = 0; k < KS; ++k) wp[k] = w[k] * inv;
    }

    // single barrier: drains gll (vmcnt) + ds_writes (lgkm), then all LDS valid
    __syncthreads();

    // ---- 4. conv: pure LDS + FMA, coalesced stores ----
    const int h    = lane >> 4;               // head-in-group 0..3
    const int doff = lane * 4;                // float offset in 256-slice
    float* ocol = out + ((size_t)b * SEQ + s0) * DMODEL + hg * DBLK + doff;

#pragma unroll
    for (int i = 0; i < TTILE / 4; ++i) {     // 8 output rows per wave
        const int sl = wave + i * 4;
        const float* wp = &fwl[sl * FW + h * KS];   // broadcast to 16 lanes
        float4 a = make_float4(0.f, 0.f, 0.f, 0.f);
#pragma unroll
        for (int k = 0; k < KS; ++k) {
            const float wk = wp[k];
            const float4 xv = *reinterpret_cast<const float4*>(
                &xs[(sl + k) * DBLK + doff]);
            a.x += wk * xv.x;
            a.y += wk * xv.y;
            a.z += wk * xv.z;
            a.w += wk * xv.w;
        }
        *reinterpret_cast<float4*>(ocol + (size_t)sl * DMODEL) = a;
    }
}

extern "C" void kernel_launch(void* const* d_in, const int* in_sizes, int n_in,
                              void* d_out, int out_size, void* d_ws, size_t ws_size,
                              hipStream_t stream) {
    const float* x    = (const float*)d_in[0];   // [8,4096,768] fp32
    const float* filt = (const float*)d_in[1];   // [8,4096,108] fp32
    float* out        = (float*)d_out;           // [8,4096,12,64] fp32

    const int grid = BATCH * NHG * CHUNKS;       // 8 * 3 * 128 = 3072 blocks
    lightconv_kernel<<<grid, NTHREADS, 0, stream>>>(x, filt, out);
}